// Round 1
// baseline (201.874 us; speedup 1.0000x reference)
//
#include <hip/hip_runtime.h>

#define D_ 1024
#define H_ 16
#define HKV_ 4
#define B_ 2
#define S_ 1024
#define BS_ (B_*S_)
#define QKVW 1536
#define QB 64
#define NC (S_/QB)

typedef short bf8 __attribute__((ext_vector_type(8)));
typedef float f32x4 __attribute__((ext_vector_type(4)));

#define MFMA_B16(a,b,c) __builtin_amdgcn_mfma_f32_16x16x32_bf16((a),(b),(c),0,0,0)

__device__ __forceinline__ unsigned short f2b(float f) {
  unsigned int u = __float_as_uint(f);
  u += 0x7FFFu + ((u >> 16) & 1u);
  return (unsigned short)(u >> 16);
}
__device__ __forceinline__ float b2f(unsigned short h) {
  return __uint_as_float(((unsigned int)h) << 16);
}
__device__ __forceinline__ float feat(float x) { return x > 0.f ? x + 1.f : __expf(x); }

// ---------------- elementwise f32 -> bf16 ----------------
__global__ __launch_bounds__(256) void k_conv(const float* __restrict__ src,
                                              unsigned short* __restrict__ dst, int n4) {
  int i = blockIdx.x * 256 + threadIdx.x;
  if (i >= n4) return;
  float4 v = ((const float4*)src)[i];
  ushort4 o;
  o.x = f2b(v.x); o.y = f2b(v.y); o.z = f2b(v.z); o.w = f2b(v.w);
  ((ushort4*)dst)[i] = o;
}

// ------- transpose + convert: src[R][C] f32 -> dst[C][R] bf16, 64x64 tiles -------
__global__ __launch_bounds__(256) void k_tconv(const float* __restrict__ src,
                                               unsigned short* __restrict__ dst,
                                               int src_stride, int dst_stride) {
  __shared__ float tl[64][65];
  int r0 = blockIdx.y * 64, c0 = blockIdx.x * 64;
  int ty = threadIdx.x >> 4;
  int tx4 = (threadIdx.x & 15) * 4;
#pragma unroll
  for (int rep = 0; rep < 4; ++rep) {
    int r = ty + rep * 16;
    float4 v = *(const float4*)&src[(size_t)(r0 + r) * src_stride + c0 + tx4];
    tl[r][tx4] = v.x; tl[r][tx4 + 1] = v.y; tl[r][tx4 + 2] = v.z; tl[r][tx4 + 3] = v.w;
  }
  __syncthreads();
#pragma unroll
  for (int rep = 0; rep < 4; ++rep) {
    int c = ty + rep * 16;
    ushort4 o;
    o.x = f2b(tl[tx4 + 0][c]); o.y = f2b(tl[tx4 + 1][c]);
    o.z = f2b(tl[tx4 + 2][c]); o.w = f2b(tl[tx4 + 3][c]);
    *(ushort4*)&dst[(size_t)(c0 + c) * dst_stride + r0 + tx4] = o;
  }
}

// ------- bt-GEMM: C[M,N] = A[M,K] * Bt[N,K]^T (+bias). 128x128 tile, BK=32 -------
template<bool BIAS, bool OUTB>
__global__ __launch_bounds__(256) void k_gemm(const unsigned short* __restrict__ A,
                                              const unsigned short* __restrict__ Bt,
                                              const float* __restrict__ bias,
                                              void* __restrict__ C,
                                              int N, int K) {
  __shared__ __align__(16) unsigned short As[128 * 32];
  __shared__ __align__(16) unsigned short Bs[128 * 32];
  const int tid = threadIdx.x;
  const int lane = tid & 63, wave = tid >> 6;
  const int wm = wave >> 1, wn = wave & 1;
  const int row0 = blockIdx.y * 128, col0 = blockIdx.x * 128;
  const f32x4 fzero = {0.f, 0.f, 0.f, 0.f};
  f32x4 acc[4][4];
#pragma unroll
  for (int i = 0; i < 4; ++i)
#pragma unroll
    for (int j = 0; j < 4; ++j) acc[i][j] = fzero;
  const int lr = lane & 15, lq = lane >> 4, lk = lq * 8;
  for (int k0 = 0; k0 < K; k0 += 32) {
#pragma unroll
    for (int i = 0; i < 2; ++i) {
      int e = (tid + i * 256) * 8;
      int r = e >> 5, c = e & 31;
      *(uint4*)&As[e] = *(const uint4*)&A[(size_t)(row0 + r) * K + k0 + c];
      *(uint4*)&Bs[e] = *(const uint4*)&Bt[(size_t)(col0 + r) * K + k0 + c];
    }
    __syncthreads();
    bf8 af[4], bfr[4];
#pragma unroll
    for (int mi = 0; mi < 4; ++mi)
      af[mi] = *(const bf8*)&As[(wm * 64 + mi * 16 + lr) * 32 + lk];
#pragma unroll
    for (int ni = 0; ni < 4; ++ni)
      bfr[ni] = *(const bf8*)&Bs[(wn * 64 + ni * 16 + lr) * 32 + lk];
#pragma unroll
    for (int mi = 0; mi < 4; ++mi)
#pragma unroll
      for (int ni = 0; ni < 4; ++ni)
        acc[mi][ni] = MFMA_B16(af[mi], bfr[ni], acc[mi][ni]);
    __syncthreads();
  }
#pragma unroll
  for (int mi = 0; mi < 4; ++mi)
#pragma unroll
    for (int ni = 0; ni < 4; ++ni) {
      int col = col0 + wn * 64 + ni * 16 + lr;
      float bv = BIAS ? bias[col] : 0.f;
#pragma unroll
      for (int r = 0; r < 4; ++r) {
        int row = row0 + wm * 64 + mi * 16 + lq * 4 + r;
        float v = acc[mi][ni][r] + bv;
        if (OUTB) ((unsigned short*)C)[(size_t)row * N + col] = f2b(v);
        else      ((float*)C)[(size_t)row * N + col] = v;
      }
    }
}

// ------- fused qkv bias: [bq | bk@Wce | bv@Wce] -------
__global__ __launch_bounds__(256) void k_bias(const float* __restrict__ bq,
                                              const float* __restrict__ bk,
                                              const float* __restrict__ bv,
                                              const float* __restrict__ Wce,
                                              float* __restrict__ bias) {
  int t = blockIdx.x * 256 + threadIdx.x;
  if (t >= QKVW) return;
  if (t < 1024) { bias[t] = bq[t]; return; }
  const float* b = (t < 1280) ? bk : bv;
  int n = (t < 1280) ? (t - 1024) : (t - 1280);
  float s = 0.f;
  for (int j = 0; j < 256; ++j) s += b[j] * Wce[j * 256 + n];
  bias[t] = s;
}

// ------- v section of qkv -> vt[b][g][d][s] bf16 -------
__global__ __launch_bounds__(256) void k_vt(const float* __restrict__ qkv,
                                            unsigned short* __restrict__ vt) {
  __shared__ float tl[64][65];
  int s0 = blockIdx.x * 64, g = blockIdx.y, b = blockIdx.z;
  int ty = threadIdx.x >> 4, tx4 = (threadIdx.x & 15) * 4;
#pragma unroll
  for (int rep = 0; rep < 4; ++rep) {
    int sr = ty + rep * 16;
    float4 v = *(const float4*)&qkv[(size_t)(b * S_ + s0 + sr) * QKVW + 1280 + g * 64 + tx4];
    tl[sr][tx4] = v.x; tl[sr][tx4 + 1] = v.y; tl[sr][tx4 + 2] = v.z; tl[sr][tx4 + 3] = v.w;
  }
  __syncthreads();
#pragma unroll
  for (int rep = 0; rep < 4; ++rep) {
    int d = ty + rep * 16;
    ushort4 o;
    o.x = f2b(tl[tx4 + 0][d]); o.y = f2b(tl[tx4 + 1][d]);
    o.z = f2b(tl[tx4 + 2][d]); o.w = f2b(tl[tx4 + 3][d]);
    *(ushort4*)&vt[((size_t)(b * HKV_ + g) * 64 + d) * S_ + s0 + tx4] = o;
  }
}

// ------- kernel A: per-chunk KV sums St_c[d][f], z_c[f] -------
__global__ __launch_bounds__(256) void k_kvsum(const float* __restrict__ qkv,
                                               const unsigned short* __restrict__ vt,
                                               float* __restrict__ stc) {
  __shared__ float Kf[64 * 64];
  __shared__ __align__(16) unsigned short Vl[64 * 64];
  int c = blockIdx.x, g = blockIdx.y, b = blockIdx.z;
  int tid = threadIdx.x;
  int s0 = c * QB;
  {
    int j = tid >> 2, f0 = (tid & 3) * 16;
    const float* kr = &qkv[(size_t)(b * S_ + s0 + j) * QKVW + 1024 + g * 64 + f0];
#pragma unroll
    for (int e = 0; e < 16; e += 4) {
      float4 v = *(const float4*)(kr + e);
      Kf[j * 64 + f0 + e + 0] = feat(v.x);
      Kf[j * 64 + f0 + e + 1] = feat(v.y);
      Kf[j * 64 + f0 + e + 2] = feat(v.z);
      Kf[j * 64 + f0 + e + 3] = feat(v.w);
    }
    const unsigned short* vbase = &vt[((size_t)(b * HKV_ + g) * 64) * S_ + s0];
#pragma unroll
    for (int i = 0; i < 2; ++i) {
      int cc = tid + i * 256;
      int d = cc >> 3, col = (cc & 7) * 8;
      *(uint4*)&Vl[cc * 8] = *(const uint4*)&vbase[(size_t)d * S_ + col];
    }
  }
  __syncthreads();
  int d = tid >> 2, f0 = (tid & 3) * 16;
  float acc[16];
#pragma unroll
  for (int e = 0; e < 16; ++e) acc[e] = 0.f;
#pragma unroll 4
  for (int j = 0; j < QB; ++j) {
    float vv = b2f(Vl[d * 64 + j]);
    const float* kfr = &Kf[j * 64 + f0];
#pragma unroll
    for (int e = 0; e < 16; ++e) acc[e] += vv * kfr[e];
  }
  size_t base = ((size_t)((b * HKV_ + g) * NC + c) * 65 + d) * 64 + f0;
#pragma unroll
  for (int e = 0; e < 16; ++e) stc[base + e] = acc[e];
  if (tid < 64) {
    float z = 0.f;
    for (int j = 0; j < QB; ++j) z += Kf[j * 64 + tid];
    stc[((size_t)((b * HKV_ + g) * NC + c) * 65 + 64) * 64 + tid] = z;
  }
}

// ------- kernel B: exclusive prefix over chunks -------
__global__ __launch_bounds__(256) void k_scan(const float* __restrict__ stc,
                                              unsigned short* __restrict__ stp,
                                              float* __restrict__ zp) {
  int bg = blockIdx.x;
  for (int e = threadIdx.x; e < 65 * 64; e += 256) {
    int d = e >> 6, f = e & 63;
    float run = 0.f;
    for (int c = 0; c < NC; ++c) {
      float v = stc[((size_t)(bg * NC + c) * 65 + d) * 64 + f];
      if (d < 64) stp[(size_t)(bg * NC + c) * 4096 + e] = f2b(run);
      else zp[(bg * NC + c) * 64 + f] = run;
      run += v;
    }
  }
}

// ------- kernel C: per-(chunk, head) attention -------
__global__ __launch_bounds__(256) void k_attn(const float* __restrict__ qkv,
                                              const unsigned short* __restrict__ vt,
                                              const unsigned short* __restrict__ stp,
                                              const float* __restrict__ zp,
                                              unsigned short* __restrict__ ob) {
  __shared__ __align__(16) unsigned short Qf[64 * 64];
  __shared__ __align__(16) unsigned short Kf[64 * 64];
  __shared__ __align__(16) unsigned short Vl[64 * 64];
  __shared__ __align__(16) unsigned short Sl[64 * 64];
  __shared__ __align__(16) unsigned short P[64 * 64];
  __shared__ float zl[64];
  __shared__ float den[64];
  int c = blockIdx.x, h = blockIdx.y, b = blockIdx.z;
  int g = h >> 2;
  int tid = threadIdx.x, lane = tid & 63, wave = tid >> 6;
  int s0 = c * QB;
  {
    int j = tid >> 2, f0 = (tid & 3) * 16;
    const float* qr = &qkv[(size_t)(b * S_ + s0 + j) * QKVW + h * 64 + f0];
    const float* kr = &qkv[(size_t)(b * S_ + s0 + j) * QKVW + 1024 + g * 64 + f0];
#pragma unroll
    for (int e = 0; e < 16; e += 4) {
      float4 q4 = *(const float4*)(qr + e);
      float4 k4 = *(const float4*)(kr + e);
      Qf[j * 64 + f0 + e + 0] = f2b(feat(q4.x));
      Qf[j * 64 + f0 + e + 1] = f2b(feat(q4.y));
      Qf[j * 64 + f0 + e + 2] = f2b(feat(q4.z));
      Qf[j * 64 + f0 + e + 3] = f2b(feat(q4.w));
      Kf[j * 64 + f0 + e + 0] = f2b(feat(k4.x));
      Kf[j * 64 + f0 + e + 1] = f2b(feat(k4.y));
      Kf[j * 64 + f0 + e + 2] = f2b(feat(k4.z));
      Kf[j * 64 + f0 + e + 3] = f2b(feat(k4.w));
    }
    const unsigned short* vbase = &vt[((size_t)(b * HKV_ + g) * 64) * S_ + s0];
    const unsigned short* sbase = &stp[(size_t)((b * HKV_ + g) * NC + c) * 4096];
#pragma unroll
    for (int i = 0; i < 2; ++i) {
      int cc = tid + i * 256;
      int d = cc >> 3, col = (cc & 7) * 8;
      *(uint4*)&Vl[cc * 8] = *(const uint4*)&vbase[(size_t)d * S_ + col];
      *(uint4*)&Sl[cc * 8] = *(const uint4*)&sbase[cc * 8];
    }
    if (tid < 64) zl[tid] = zp[((b * HKV_ + g) * NC + c) * 64 + tid];
  }
  __syncthreads();
  const int lr = lane & 15, lq = lane >> 4, lk = lq * 8;
  const int rw = wave * 16;
  const f32x4 fzero = {0.f, 0.f, 0.f, 0.f};
  bf8 aQ[2];
#pragma unroll
  for (int kk = 0; kk < 2; ++kk)
    aQ[kk] = *(const bf8*)&Qf[(rw + lr) * 64 + kk * 32 + lk];
  f32x4 sc[4];
#pragma unroll
  for (int nj = 0; nj < 4; ++nj) sc[nj] = fzero;
#pragma unroll
  for (int nj = 0; nj < 4; ++nj)
#pragma unroll
    for (int kk = 0; kk < 2; ++kk) {
      bf8 bk8 = *(const bf8*)&Kf[(nj * 16 + lr) * 64 + kk * 32 + lk];
      sc[nj] = MFMA_B16(aQ[kk], bk8, sc[nj]);
    }
  // causal mask (diag included) + store P as bf16
#pragma unroll
  for (int nj = 0; nj < 4; ++nj)
#pragma unroll
    for (int r = 0; r < 4; ++r) {
      int i = rw + lq * 4 + r;
      int j = nj * 16 + lr;
      float v = (j <= i) ? sc[nj][r] : 0.f;
      P[i * 64 + j] = f2b(v);
    }
  __syncthreads();
  // den[i] = rowsum(P[i]) + Qf[i] . z_prev
  {
    int i = tid >> 2, q = tid & 3, f0 = q * 16;
    float s = 0.f;
#pragma unroll
    for (int e = 0; e < 16; ++e) s += b2f(P[i * 64 + f0 + e]);
#pragma unroll
    for (int e = 0; e < 16; ++e) s += b2f(Qf[i * 64 + f0 + e]) * zl[f0 + e];
    s += __shfl_xor(s, 1);
    s += __shfl_xor(s, 2);
    if (q == 0) den[i] = s;
  }
  __syncthreads();
  // O = P @ V + Qf @ S_prev
  f32x4 oa[4];
#pragma unroll
  for (int nd = 0; nd < 4; ++nd) oa[nd] = fzero;
  bf8 aP[2];
#pragma unroll
  for (int kk = 0; kk < 2; ++kk)
    aP[kk] = *(const bf8*)&P[(rw + lr) * 64 + kk * 32 + lk];
#pragma unroll
  for (int nd = 0; nd < 4; ++nd)
#pragma unroll
    for (int kk = 0; kk < 2; ++kk) {
      bf8 bS = *(const bf8*)&Sl[(nd * 16 + lr) * 64 + kk * 32 + lk];
      oa[nd] = MFMA_B16(aQ[kk], bS, oa[nd]);
      bf8 bV = *(const bf8*)&Vl[(nd * 16 + lr) * 64 + kk * 32 + lk];
      oa[nd] = MFMA_B16(aP[kk], bV, oa[nd]);
    }
#pragma unroll
  for (int nd = 0; nd < 4; ++nd)
#pragma unroll
    for (int r = 0; r < 4; ++r) {
      int i = rw + lq * 4 + r;
      int dd = nd * 16 + lr;
      float o = oa[nd][r] / (den[i] + 1e-6f);
      ob[(size_t)(b * S_ + s0 + i) * D_ + h * 64 + dd] = f2b(o);
    }
}

// ------- residual + LayerNorm -------
__global__ __launch_bounds__(256) void k_ln(const float* __restrict__ x,
                                            const float* __restrict__ o2,
                                            const float* __restrict__ gamma,
                                            const float* __restrict__ beta,
                                            float* __restrict__ out) {
  int row = blockIdx.x, tid = threadIdx.x;
  float4 xv = ((const float4*)(x + (size_t)row * D_))[tid];
  float4 ov = ((const float4*)(o2 + (size_t)row * D_))[tid];
  float4 y;
  y.x = xv.x + ov.x; y.y = xv.y + ov.y; y.z = xv.z + ov.z; y.w = xv.w + ov.w;
  float s = y.x + y.y + y.z + y.w;
  float ss = y.x * y.x + y.y * y.y + y.z * y.z + y.w * y.w;
#pragma unroll
  for (int off = 32; off > 0; off >>= 1) {
    s += __shfl_down(s, off);
    ss += __shfl_down(ss, off);
  }
  __shared__ float red[8];
  int lane = tid & 63, wave = tid >> 6;
  if (lane == 0) { red[wave] = s; red[4 + wave] = ss; }
  __syncthreads();
  if (tid == 0) {
    red[0] = red[0] + red[1] + red[2] + red[3];
    red[4] = red[4] + red[5] + red[6] + red[7];
  }
  __syncthreads();
  float mu = red[0] * (1.f / D_);
  float var = red[4] * (1.f / D_) - mu * mu;
  float rs = rsqrtf(var + 1e-5f);
  float4 g4 = ((const float4*)gamma)[tid];
  float4 b4 = ((const float4*)beta)[tid];
  float4 o;
  o.x = (y.x - mu) * rs * g4.x + b4.x;
  o.y = (y.y - mu) * rs * g4.y + b4.y;
  o.z = (y.z - mu) * rs * g4.z + b4.z;
  o.w = (y.w - mu) * rs * g4.w + b4.w;
  ((float4*)(out + (size_t)row * D_))[tid] = o;
}

extern "C" void kernel_launch(void* const* d_in, const int* in_sizes, int n_in,
                              void* d_out, int out_size, void* d_ws, size_t ws_size,
                              hipStream_t stream) {
  const float* x     = (const float*)d_in[0];
  const float* Wq    = (const float*)d_in[1];
  const float* bq    = (const float*)d_in[2];
  const float* Wk    = (const float*)d_in[3];
  const float* bk    = (const float*)d_in[4];
  const float* Wv    = (const float*)d_in[5];
  const float* bv    = (const float*)d_in[6];
  const float* Wc    = (const float*)d_in[7];
  const float* We    = (const float*)d_in[8];
  const float* Wo    = (const float*)d_in[9];
  const float* bo    = (const float*)d_in[10];
  const float* gamma = (const float*)d_in[11];
  const float* beta  = (const float*)d_in[12];

  char* p = (char*)d_ws;
  size_t off = 0;
  auto carve = [&](size_t bytes) {
    void* r = p + off;
    off = (off + bytes + 255) & ~(size_t)255;
    return r;
  };
  unsigned short* xb     = (unsigned short*)carve((size_t)BS_ * D_ * 2);
  unsigned short* Wqkv_t = (unsigned short*)carve((size_t)QKVW * D_ * 2);
  unsigned short* Wo_t   = (unsigned short*)carve((size_t)D_ * D_ * 2);
  float*          biasq  = (float*)carve(QKVW * 4);
  float*          qkv    = (float*)carve((size_t)BS_ * QKVW * 4);
  unsigned short* Wc_b   = (unsigned short*)carve(256 * 64 * 2);
  unsigned short* We_t   = (unsigned short*)carve(256 * 64 * 2);
  float*          Wce    = (float*)carve(256 * 256 * 4);
  unsigned short* Wce_t  = (unsigned short*)carve(256 * 256 * 2);
  unsigned short* Wk_b   = (unsigned short*)carve(1024 * 256 * 2);
  unsigned short* Wv_b   = (unsigned short*)carve(1024 * 256 * 2);
  unsigned short* vtb    = (unsigned short*)carve((size_t)8 * 64 * S_ * 2);
  float*          stc    = (float*)carve((size_t)8 * NC * 65 * 64 * 4);
  unsigned short* stp    = (unsigned short*)carve((size_t)8 * NC * 4096 * 2);
  float*          zp     = (float*)carve((size_t)8 * NC * 64 * 4);
  unsigned short* obuf   = (unsigned short*)carve((size_t)BS_ * D_ * 2);
  float*          o2     = qkv;  // qkv dead after attention; reuse (8MB <= 12MB)

  // --- weight preprocessing ---
  k_conv<<<(BS_ * D_ / 4 + 255) / 256, 256, 0, stream>>>(x, xb, BS_ * D_ / 4);
  k_conv<<<16, 256, 0, stream>>>(Wc, Wc_b, 256 * 64 / 4);
  k_tconv<<<dim3(4, 1), 256, 0, stream>>>(We, We_t, 256, 64);        // We[64,256] -> [256,64]
  k_conv<<<256, 256, 0, stream>>>(Wk, Wk_b, 1024 * 256 / 4);
  k_conv<<<256, 256, 0, stream>>>(Wv, Wv_b, 1024 * 256 / 4);
  // Wce = Wc @ We   [256,256]
  k_gemm<false, false><<<dim3(2, 2), 256, 0, stream>>>(Wc_b, We_t, nullptr, Wce, 256, 64);
  k_tconv<<<dim3(4, 4), 256, 0, stream>>>(Wce, Wce_t, 256, 256);
  // Wk2^T = Wce^T @ Wk^T  -> rows [1024,1280) of Wqkv_t ; same for V
  k_gemm<false, true><<<dim3(8, 2), 256, 0, stream>>>(Wce_t, Wk_b, nullptr, Wqkv_t + 1024 * 1024, 1024, 256);
  k_gemm<false, true><<<dim3(8, 2), 256, 0, stream>>>(Wce_t, Wv_b, nullptr, Wqkv_t + 1280 * 1024, 1024, 256);
  k_tconv<<<dim3(16, 16), 256, 0, stream>>>(Wq, Wqkv_t, 1024, 1024); // rows [0,1024)
  k_tconv<<<dim3(16, 16), 256, 0, stream>>>(Wo, Wo_t, 1024, 1024);
  k_bias<<<6, 256, 0, stream>>>(bq, bk, bv, Wce, biasq);

  // --- fused QKV projection: qkv[2048,1536] ---
  k_gemm<true, false><<<dim3(12, 16), 256, 0, stream>>>(xb, Wqkv_t, biasq, qkv, QKVW, 1024);

  // --- attention ---
  k_vt<<<dim3(16, HKV_, B_), 256, 0, stream>>>(qkv, vtb);
  k_kvsum<<<dim3(NC, HKV_, B_), 256, 0, stream>>>(qkv, vtb, stc);
  k_scan<<<8, 256, 0, stream>>>(stc, stp, zp);
  k_attn<<<dim3(NC, H_, B_), 256, 0, stream>>>(qkv, vtb, stp, zp, obuf);

  // --- output projection + residual/LN ---
  k_gemm<true, false><<<dim3(8, 16), 256, 0, stream>>>(obuf, Wo_t, bo, o2, 1024, 1024);
  k_ln<<<BS_, 256, 0, stream>>>(x, o2, gamma, beta, (float*)d_out);
}

// Round 2
// 138.002 us; speedup vs baseline: 1.4628x; 1.4628x over previous
//
#include <hip/hip_runtime.h>

#define D_ 1024
#define H_ 16
#define HKV_ 4
#define B_ 2
#define S_ 1024
#define BS_ (B_*S_)
#define QKVW 1536
#define QB 64
#define NC (S_/QB)

typedef short bf8 __attribute__((ext_vector_type(8)));
typedef float f32x4 __attribute__((ext_vector_type(4)));

#define MFMA_B16(a,b,c) __builtin_amdgcn_mfma_f32_16x16x32_bf16((a),(b),(c),0,0,0)

__device__ __forceinline__ unsigned short f2b(float f) {
  unsigned int u = __float_as_uint(f);
  u += 0x7FFFu + ((u >> 16) & 1u);
  return (unsigned short)(u >> 16);
}
__device__ __forceinline__ float b2f(unsigned short h) {
  return __uint_as_float(((unsigned int)h) << 16);
}
__device__ __forceinline__ float feat(float x) { return x > 0.f ? x + 1.f : __expf(x); }

// ---------------- elementwise f32 -> bf16 ----------------
__global__ __launch_bounds__(256) void k_conv(const float* __restrict__ src,
                                              unsigned short* __restrict__ dst, int n4) {
  int i = blockIdx.x * 256 + threadIdx.x;
  if (i >= n4) return;
  float4 v = ((const float4*)src)[i];
  ushort4 o;
  o.x = f2b(v.x); o.y = f2b(v.y); o.z = f2b(v.z); o.w = f2b(v.w);
  ((ushort4*)dst)[i] = o;
}

// ------- transpose + convert: src[R][C] f32 -> dst[C][R] bf16, 64x64 tiles -------
__global__ __launch_bounds__(256) void k_tconv(const float* __restrict__ src,
                                               unsigned short* __restrict__ dst,
                                               int src_stride, int dst_stride) {
  __shared__ float tl[64][65];
  int r0 = blockIdx.y * 64, c0 = blockIdx.x * 64;
  int ty = threadIdx.x >> 4;
  int tx4 = (threadIdx.x & 15) * 4;
#pragma unroll
  for (int rep = 0; rep < 4; ++rep) {
    int r = ty + rep * 16;
    float4 v = *(const float4*)&src[(size_t)(r0 + r) * src_stride + c0 + tx4];
    tl[r][tx4] = v.x; tl[r][tx4 + 1] = v.y; tl[r][tx4 + 2] = v.z; tl[r][tx4 + 3] = v.w;
  }
  __syncthreads();
#pragma unroll
  for (int rep = 0; rep < 4; ++rep) {
    int c = ty + rep * 16;
    ushort4 o;
    o.x = f2b(tl[tx4 + 0][c]); o.y = f2b(tl[tx4 + 1][c]);
    o.z = f2b(tl[tx4 + 2][c]); o.w = f2b(tl[tx4 + 3][c]);
    *(ushort4*)&dst[(size_t)(c0 + c) * dst_stride + r0 + tx4] = o;
  }
}

// ------- bt-GEMM: C[M,N] = A[M,K] * Bt[N,K]^T (+bias). 128x128 tile, BK=32 -------
template<bool BIAS, bool OUTB>
__global__ __launch_bounds__(256) void k_gemm(const unsigned short* __restrict__ A,
                                              const unsigned short* __restrict__ Bt,
                                              const float* __restrict__ bias,
                                              void* __restrict__ C,
                                              int N, int K) {
  __shared__ __align__(16) unsigned short As[128 * 32];
  __shared__ __align__(16) unsigned short Bs[128 * 32];
  const int tid = threadIdx.x;
  const int lane = tid & 63, wave = tid >> 6;
  const int wm = wave >> 1, wn = wave & 1;
  const int row0 = blockIdx.y * 128, col0 = blockIdx.x * 128;
  const f32x4 fzero = {0.f, 0.f, 0.f, 0.f};
  f32x4 acc[4][4];
#pragma unroll
  for (int i = 0; i < 4; ++i)
#pragma unroll
    for (int j = 0; j < 4; ++j) acc[i][j] = fzero;
  const int lr = lane & 15, lq = lane >> 4, lk = lq * 8;
  for (int k0 = 0; k0 < K; k0 += 32) {
#pragma unroll
    for (int i = 0; i < 2; ++i) {
      int e = (tid + i * 256) * 8;
      int r = e >> 5, c = e & 31;
      *(uint4*)&As[e] = *(const uint4*)&A[(size_t)(row0 + r) * K + k0 + c];
      *(uint4*)&Bs[e] = *(const uint4*)&Bt[(size_t)(col0 + r) * K + k0 + c];
    }
    __syncthreads();
    bf8 af[4], bfr[4];
#pragma unroll
    for (int mi = 0; mi < 4; ++mi)
      af[mi] = *(const bf8*)&As[(wm * 64 + mi * 16 + lr) * 32 + lk];
#pragma unroll
    for (int ni = 0; ni < 4; ++ni)
      bfr[ni] = *(const bf8*)&Bs[(wn * 64 + ni * 16 + lr) * 32 + lk];
#pragma unroll
    for (int mi = 0; mi < 4; ++mi)
#pragma unroll
      for (int ni = 0; ni < 4; ++ni)
        acc[mi][ni] = MFMA_B16(af[mi], bfr[ni], acc[mi][ni]);
    __syncthreads();
  }
#pragma unroll
  for (int mi = 0; mi < 4; ++mi)
#pragma unroll
    for (int ni = 0; ni < 4; ++ni) {
      int col = col0 + wn * 64 + ni * 16 + lr;
      float bv = BIAS ? bias[col] : 0.f;
#pragma unroll
      for (int r = 0; r < 4; ++r) {
        int row = row0 + wm * 64 + mi * 16 + lq * 4 + r;
        float v = acc[mi][ni][r] + bv;
        if (OUTB) ((unsigned short*)C)[(size_t)row * N + col] = f2b(v);
        else      ((float*)C)[(size_t)row * N + col] = v;
      }
    }
}

// ------- fused qkv bias: [bq | bk@Wce | bv@Wce] -------
__global__ __launch_bounds__(256) void k_bias(const float* __restrict__ bq,
                                              const float* __restrict__ bk,
                                              const float* __restrict__ bv,
                                              const float* __restrict__ Wce,
                                              float* __restrict__ bias) {
  int t = blockIdx.x * 256 + threadIdx.x;
  if (t >= QKVW) return;
  if (t < 1024) { bias[t] = bq[t]; return; }
  const float* b = (t < 1280) ? bk : bv;
  int n = (t < 1280) ? (t - 1024) : (t - 1280);
  float s = 0.f;
  for (int j = 0; j < 256; ++j) s += b[j] * Wce[j * 256 + n];
  bias[t] = s;
}

// ------- v section of qkv -> vt[b][g][d][s] bf16 -------
__global__ __launch_bounds__(256) void k_vt(const float* __restrict__ qkv,
                                            unsigned short* __restrict__ vt) {
  __shared__ float tl[64][65];
  int s0 = blockIdx.x * 64, g = blockIdx.y, b = blockIdx.z;
  int ty = threadIdx.x >> 4, tx4 = (threadIdx.x & 15) * 4;
#pragma unroll
  for (int rep = 0; rep < 4; ++rep) {
    int sr = ty + rep * 16;
    float4 v = *(const float4*)&qkv[(size_t)(b * S_ + s0 + sr) * QKVW + 1280 + g * 64 + tx4];
    tl[sr][tx4] = v.x; tl[sr][tx4 + 1] = v.y; tl[sr][tx4 + 2] = v.z; tl[sr][tx4 + 3] = v.w;
  }
  __syncthreads();
#pragma unroll
  for (int rep = 0; rep < 4; ++rep) {
    int d = ty + rep * 16;
    ushort4 o;
    o.x = f2b(tl[tx4 + 0][d]); o.y = f2b(tl[tx4 + 1][d]);
    o.z = f2b(tl[tx4 + 2][d]); o.w = f2b(tl[tx4 + 3][d]);
    *(ushort4*)&vt[((size_t)(b * HKV_ + g) * 64 + d) * S_ + s0 + tx4] = o;
  }
}

// ------- kernel A: per-chunk KV sums St_c[d][f], z_c[f] -------
__global__ __launch_bounds__(256) void k_kvsum(const float* __restrict__ qkv,
                                               const unsigned short* __restrict__ vt,
                                               float* __restrict__ stc) {
  __shared__ float Kf[64 * 64];
  __shared__ __align__(16) unsigned short Vl[64 * 64];
  int c = blockIdx.x, g = blockIdx.y, b = blockIdx.z;
  int tid = threadIdx.x;
  int s0 = c * QB;
  {
    int j = tid >> 2, f0 = (tid & 3) * 16;
    const float* kr = &qkv[(size_t)(b * S_ + s0 + j) * QKVW + 1024 + g * 64 + f0];
#pragma unroll
    for (int e = 0; e < 16; e += 4) {
      float4 v = *(const float4*)(kr + e);
      Kf[j * 64 + f0 + e + 0] = feat(v.x);
      Kf[j * 64 + f0 + e + 1] = feat(v.y);
      Kf[j * 64 + f0 + e + 2] = feat(v.z);
      Kf[j * 64 + f0 + e + 3] = feat(v.w);
    }
    const unsigned short* vbase = &vt[((size_t)(b * HKV_ + g) * 64) * S_ + s0];
#pragma unroll
    for (int i = 0; i < 2; ++i) {
      int cc = tid + i * 256;
      int d = cc >> 3, col = (cc & 7) * 8;
      *(uint4*)&Vl[cc * 8] = *(const uint4*)&vbase[(size_t)d * S_ + col];
    }
  }
  __syncthreads();
  int d = tid >> 2, f0 = (tid & 3) * 16;
  float acc[16];
#pragma unroll
  for (int e = 0; e < 16; ++e) acc[e] = 0.f;
#pragma unroll 4
  for (int j = 0; j < QB; ++j) {
    float vv = b2f(Vl[d * 64 + j]);
    const float* kfr = &Kf[j * 64 + f0];
#pragma unroll
    for (int e = 0; e < 16; ++e) acc[e] += vv * kfr[e];
  }
  size_t base = ((size_t)((b * HKV_ + g) * NC + c) * 65 + d) * 64 + f0;
#pragma unroll
  for (int e = 0; e < 16; ++e) stc[base + e] = acc[e];
  if (tid < 64) {
    float z = 0.f;
    for (int j = 0; j < QB; ++j) z += Kf[j * 64 + tid];
    stc[((size_t)((b * HKV_ + g) * NC + c) * 65 + 64) * 64 + tid] = z;
  }
}

// ------- kernel B: exclusive prefix over chunks — one thread per element -------
// 8 bg * 65*64 elements = 33280 threads; 16 independent loads each, fully
// latency-hidden by TLP. (R1 fix: old version used 8 blocks -> 0.3% occupancy,
// 71 us. This one: 130 blocks, coalesced.)
__global__ __launch_bounds__(256) void k_scan(const float* __restrict__ stc,
                                              unsigned short* __restrict__ stp,
                                              float* __restrict__ zp) {
  int t = blockIdx.x * 256 + threadIdx.x;
  if (t >= 8 * 65 * 64) return;
  int bg = t / (65 * 64);
  int e = t - bg * (65 * 64);
  int d = e >> 6, f = e & 63;
  float run = 0.f;
#pragma unroll
  for (int c = 0; c < NC; ++c) {
    if (d < 64) stp[(size_t)(bg * NC + c) * 4096 + e] = f2b(run);
    else        zp[(bg * NC + c) * 64 + f] = run;
    run += stc[((size_t)(bg * NC + c) * 65 + d) * 64 + f];
  }
}

// ------- kernel C: per-(chunk, head) attention -------
__global__ __launch_bounds__(256) void k_attn(const float* __restrict__ qkv,
                                              const unsigned short* __restrict__ vt,
                                              const unsigned short* __restrict__ stp,
                                              const float* __restrict__ zp,
                                              unsigned short* __restrict__ ob) {
  __shared__ __align__(16) unsigned short Qf[64 * 64];
  __shared__ __align__(16) unsigned short Kf[64 * 64];
  __shared__ __align__(16) unsigned short Vl[64 * 64];
  __shared__ __align__(16) unsigned short Sl[64 * 64];
  __shared__ __align__(16) unsigned short P[64 * 64];
  __shared__ float zl[64];
  __shared__ float den[64];
  int c = blockIdx.x, h = blockIdx.y, b = blockIdx.z;
  int g = h >> 2;
  int tid = threadIdx.x, lane = tid & 63, wave = tid >> 6;
  int s0 = c * QB;
  {
    int j = tid >> 2, f0 = (tid & 3) * 16;
    const float* qr = &qkv[(size_t)(b * S_ + s0 + j) * QKVW + h * 64 + f0];
    const float* kr = &qkv[(size_t)(b * S_ + s0 + j) * QKVW + 1024 + g * 64 + f0];
#pragma unroll
    for (int e = 0; e < 16; e += 4) {
      float4 q4 = *(const float4*)(qr + e);
      float4 k4 = *(const float4*)(kr + e);
      Qf[j * 64 + f0 + e + 0] = f2b(feat(q4.x));
      Qf[j * 64 + f0 + e + 1] = f2b(feat(q4.y));
      Qf[j * 64 + f0 + e + 2] = f2b(feat(q4.z));
      Qf[j * 64 + f0 + e + 3] = f2b(feat(q4.w));
      Kf[j * 64 + f0 + e + 0] = f2b(feat(k4.x));
      Kf[j * 64 + f0 + e + 1] = f2b(feat(k4.y));
      Kf[j * 64 + f0 + e + 2] = f2b(feat(k4.z));
      Kf[j * 64 + f0 + e + 3] = f2b(feat(k4.w));
    }
    const unsigned short* vbase = &vt[((size_t)(b * HKV_ + g) * 64) * S_ + s0];
    const unsigned short* sbase = &stp[(size_t)((b * HKV_ + g) * NC + c) * 4096];
#pragma unroll
    for (int i = 0; i < 2; ++i) {
      int cc = tid + i * 256;
      int d = cc >> 3, col = (cc & 7) * 8;
      *(uint4*)&Vl[cc * 8] = *(const uint4*)&vbase[(size_t)d * S_ + col];
      *(uint4*)&Sl[cc * 8] = *(const uint4*)&sbase[cc * 8];
    }
    if (tid < 64) zl[tid] = zp[((b * HKV_ + g) * NC + c) * 64 + tid];
  }
  __syncthreads();
  const int lr = lane & 15, lq = lane >> 4, lk = lq * 8;
  const int rw = wave * 16;
  const f32x4 fzero = {0.f, 0.f, 0.f, 0.f};
  bf8 aQ[2];
#pragma unroll
  for (int kk = 0; kk < 2; ++kk)
    aQ[kk] = *(const bf8*)&Qf[(rw + lr) * 64 + kk * 32 + lk];
  f32x4 sc[4];
#pragma unroll
  for (int nj = 0; nj < 4; ++nj) sc[nj] = fzero;
#pragma unroll
  for (int nj = 0; nj < 4; ++nj)
#pragma unroll
    for (int kk = 0; kk < 2; ++kk) {
      bf8 bk8 = *(const bf8*)&Kf[(nj * 16 + lr) * 64 + kk * 32 + lk];
      sc[nj] = MFMA_B16(aQ[kk], bk8, sc[nj]);
    }
  // causal mask (diag included) + store P as bf16
#pragma unroll
  for (int nj = 0; nj < 4; ++nj)
#pragma unroll
    for (int r = 0; r < 4; ++r) {
      int i = rw + lq * 4 + r;
      int j = nj * 16 + lr;
      float v = (j <= i) ? sc[nj][r] : 0.f;
      P[i * 64 + j] = f2b(v);
    }
  __syncthreads();
  // den[i] = rowsum(P[i]) + Qf[i] . z_prev
  {
    int i = tid >> 2, q = tid & 3, f0 = q * 16;
    float s = 0.f;
#pragma unroll
    for (int e = 0; e < 16; ++e) s += b2f(P[i * 64 + f0 + e]);
#pragma unroll
    for (int e = 0; e < 16; ++e) s += b2f(Qf[i * 64 + f0 + e]) * zl[f0 + e];
    s += __shfl_xor(s, 1);
    s += __shfl_xor(s, 2);
    if (q == 0) den[i] = s;
  }
  __syncthreads();
  // O = P @ V + Qf @ S_prev
  f32x4 oa[4];
#pragma unroll
  for (int nd = 0; nd < 4; ++nd) oa[nd] = fzero;
  bf8 aP[2];
#pragma unroll
  for (int kk = 0; kk < 2; ++kk)
    aP[kk] = *(const bf8*)&P[(rw + lr) * 64 + kk * 32 + lk];
#pragma unroll
  for (int nd = 0; nd < 4; ++nd)
#pragma unroll
    for (int kk = 0; kk < 2; ++kk) {
      bf8 bS = *(const bf8*)&Sl[(nd * 16 + lr) * 64 + kk * 32 + lk];
      oa[nd] = MFMA_B16(aQ[kk], bS, oa[nd]);
      bf8 bV = *(const bf8*)&Vl[(nd * 16 + lr) * 64 + kk * 32 + lk];
      oa[nd] = MFMA_B16(aP[kk], bV, oa[nd]);
    }
#pragma unroll
  for (int nd = 0; nd < 4; ++nd)
#pragma unroll
    for (int r = 0; r < 4; ++r) {
      int i = rw + lq * 4 + r;
      int dd = nd * 16 + lr;
      float o = oa[nd][r] / (den[i] + 1e-6f);
      ob[(size_t)(b * S_ + s0 + i) * D_ + h * 64 + dd] = f2b(o);
    }
}

// ------- residual + LayerNorm -------
__global__ __launch_bounds__(256) void k_ln(const float* __restrict__ x,
                                            const float* __restrict__ o2,
                                            const float* __restrict__ gamma,
                                            const float* __restrict__ beta,
                                            float* __restrict__ out) {
  int row = blockIdx.x, tid = threadIdx.x;
  float4 xv = ((const float4*)(x + (size_t)row * D_))[tid];
  float4 ov = ((const float4*)(o2 + (size_t)row * D_))[tid];
  float4 y;
  y.x = xv.x + ov.x; y.y = xv.y + ov.y; y.z = xv.z + ov.z; y.w = xv.w + ov.w;
  float s = y.x + y.y + y.z + y.w;
  float ss = y.x * y.x + y.y * y.y + y.z * y.z + y.w * y.w;
#pragma unroll
  for (int off = 32; off > 0; off >>= 1) {
    s += __shfl_down(s, off);
    ss += __shfl_down(ss, off);
  }
  __shared__ float red[8];
  int lane = tid & 63, wave = tid >> 6;
  if (lane == 0) { red[wave] = s; red[4 + wave] = ss; }
  __syncthreads();
  if (tid == 0) {
    red[0] = red[0] + red[1] + red[2] + red[3];
    red[4] = red[4] + red[5] + red[6] + red[7];
  }
  __syncthreads();
  float mu = red[0] * (1.f / D_);
  float var = red[4] * (1.f / D_) - mu * mu;
  float rs = rsqrtf(var + 1e-5f);
  float4 g4 = ((const float4*)gamma)[tid];
  float4 b4 = ((const float4*)beta)[tid];
  float4 o;
  o.x = (y.x - mu) * rs * g4.x + b4.x;
  o.y = (y.y - mu) * rs * g4.y + b4.y;
  o.z = (y.z - mu) * rs * g4.z + b4.z;
  o.w = (y.w - mu) * rs * g4.w + b4.w;
  ((float4*)(out + (size_t)row * D_))[tid] = o;
}

extern "C" void kernel_launch(void* const* d_in, const int* in_sizes, int n_in,
                              void* d_out, int out_size, void* d_ws, size_t ws_size,
                              hipStream_t stream) {
  const float* x     = (const float*)d_in[0];
  const float* Wq    = (const float*)d_in[1];
  const float* bq    = (const float*)d_in[2];
  const float* Wk    = (const float*)d_in[3];
  const float* bk    = (const float*)d_in[4];
  const float* Wv    = (const float*)d_in[5];
  const float* bv    = (const float*)d_in[6];
  const float* Wc    = (const float*)d_in[7];
  const float* We    = (const float*)d_in[8];
  const float* Wo    = (const float*)d_in[9];
  const float* bo    = (const float*)d_in[10];
  const float* gamma = (const float*)d_in[11];
  const float* beta  = (const float*)d_in[12];

  char* p = (char*)d_ws;
  size_t off = 0;
  auto carve = [&](size_t bytes) {
    void* r = p + off;
    off = (off + bytes + 255) & ~(size_t)255;
    return r;
  };
  unsigned short* xb     = (unsigned short*)carve((size_t)BS_ * D_ * 2);
  unsigned short* Wqkv_t = (unsigned short*)carve((size_t)QKVW * D_ * 2);
  unsigned short* Wo_t   = (unsigned short*)carve((size_t)D_ * D_ * 2);
  float*          biasq  = (float*)carve(QKVW * 4);
  float*          qkv    = (float*)carve((size_t)BS_ * QKVW * 4);
  unsigned short* Wc_b   = (unsigned short*)carve(256 * 64 * 2);
  unsigned short* We_t   = (unsigned short*)carve(256 * 64 * 2);
  float*          Wce    = (float*)carve(256 * 256 * 4);
  unsigned short* Wce_t  = (unsigned short*)carve(256 * 256 * 2);
  unsigned short* Wk_b   = (unsigned short*)carve(1024 * 256 * 2);
  unsigned short* Wv_b   = (unsigned short*)carve(1024 * 256 * 2);
  unsigned short* vtb    = (unsigned short*)carve((size_t)8 * 64 * S_ * 2);
  float*          stc    = (float*)carve((size_t)8 * NC * 65 * 64 * 4);
  unsigned short* stp    = (unsigned short*)carve((size_t)8 * NC * 4096 * 2);
  float*          zp     = (float*)carve((size_t)8 * NC * 64 * 4);
  unsigned short* obuf   = (unsigned short*)carve((size_t)BS_ * D_ * 2);
  float*          o2     = qkv;  // qkv dead after attention; reuse (8MB <= 12MB)

  // --- weight preprocessing ---
  k_conv<<<(BS_ * D_ / 4 + 255) / 256, 256, 0, stream>>>(x, xb, BS_ * D_ / 4);
  k_conv<<<16, 256, 0, stream>>>(Wc, Wc_b, 256 * 64 / 4);
  k_tconv<<<dim3(4, 1), 256, 0, stream>>>(We, We_t, 256, 64);        // We[64,256] -> [256,64]
  k_conv<<<256, 256, 0, stream>>>(Wk, Wk_b, 1024 * 256 / 4);
  k_conv<<<256, 256, 0, stream>>>(Wv, Wv_b, 1024 * 256 / 4);
  // Wce = Wc @ We   [256,256]
  k_gemm<false, false><<<dim3(2, 2), 256, 0, stream>>>(Wc_b, We_t, nullptr, Wce, 256, 64);
  k_tconv<<<dim3(4, 4), 256, 0, stream>>>(Wce, Wce_t, 256, 256);
  // Wk2^T = Wce^T @ Wk^T  -> rows [1024,1280) of Wqkv_t ; same for V
  k_gemm<false, true><<<dim3(8, 2), 256, 0, stream>>>(Wce_t, Wk_b, nullptr, Wqkv_t + 1024 * 1024, 1024, 256);
  k_gemm<false, true><<<dim3(8, 2), 256, 0, stream>>>(Wce_t, Wv_b, nullptr, Wqkv_t + 1280 * 1024, 1024, 256);
  k_tconv<<<dim3(16, 16), 256, 0, stream>>>(Wq, Wqkv_t, 1024, 1024); // rows [0,1024)
  k_tconv<<<dim3(16, 16), 256, 0, stream>>>(Wo, Wo_t, 1024, 1024);
  k_bias<<<6, 256, 0, stream>>>(bq, bk, bv, Wce, biasq);

  // --- fused QKV projection: qkv[2048,1536] ---
  k_gemm<true, false><<<dim3(12, 16), 256, 0, stream>>>(xb, Wqkv_t, biasq, qkv, QKVW, 1024);

  // --- attention ---
  k_vt<<<dim3(16, HKV_, B_), 256, 0, stream>>>(qkv, vtb);
  k_kvsum<<<dim3(NC, HKV_, B_), 256, 0, stream>>>(qkv, vtb, stc);
  k_scan<<<(8 * 65 * 64 + 255) / 256, 256, 0, stream>>>(stc, stp, zp);
  k_attn<<<dim3(NC, H_, B_), 256, 0, stream>>>(qkv, vtb, stp, zp, obuf);

  // --- output projection + residual/LN ---
  k_gemm<true, false><<<dim3(8, 16), 256, 0, stream>>>(obuf, Wo_t, bo, o2, 1024, 1024);
  k_ln<<<BS_, 256, 0, stream>>>(x, o2, gamma, beta, (float*)d_out);
}